// Round 1
// baseline (49.496 us; speedup 1.0000x reference)
//
#include <hip/hip_runtime.h>

// SymmetricChannel: B=128, L=64, V=4096, P=0.1
//   mask      = rand_mask < P                      (B,L)
//   any_hit   = mask.any()
//   col_hit[v]= OR over masked positions of (replacement_ids == v)
//   eos       = probs[..., 0]
//   row masked:   out[v] = col_hit[v] ? 1-eos : (v==0 ? eos : 0)
//   row unmasked: out[v] = probs[v]
//   entropy_out = entropy + (any_hit ? H2(P)+log2(L-2) : 0)

#define V_DIM   4096
#define N_ROWS  8192          // B*L
#define P_CONST 0.1f
// H2(0.1) + log2(62), computed in double, well within the 0.148 threshold
#define DELTA_CONST 6.4231919039761563f

// ---------------- kernel 1: col_hit bitmask + any_hit + entropy_out ---------
__global__ __launch_bounds__(1024)
void sc_colhit_kernel(const float* __restrict__ rand_mask,
                      const int*   __restrict__ repl,
                      const float* __restrict__ entropy,
                      unsigned*    __restrict__ colhit_out,   // V/32 = 128 words in d_ws
                      float*       __restrict__ entropy_out)  // d_out + B*L*V
{
    __shared__ unsigned colhit[V_DIM / 32];
    __shared__ unsigned anyhit;
    const int t = threadIdx.x;
    if (t < V_DIM / 32) colhit[t] = 0u;
    if (t == 0) anyhit = 0u;
    __syncthreads();

    bool local_any = false;
    #pragma unroll
    for (int k = 0; k < N_ROWS / 1024; ++k) {
        const int i = t + k * 1024;
        if (rand_mask[i] < P_CONST) {
            const int id = repl[i];
            atomicOr(&colhit[id >> 5], 1u << (id & 31));
            local_any = true;
        }
    }
    if (local_any) atomicOr(&anyhit, 1u);
    __syncthreads();

    if (t < V_DIM / 32) colhit_out[t] = colhit[t];
    const float d = anyhit ? DELTA_CONST : 0.0f;
    #pragma unroll
    for (int k = 0; k < N_ROWS / 1024; ++k) {
        const int i = t + k * 1024;
        entropy_out[i] = entropy[i] + d;
    }
}

// ---------------- kernel 2: per-row probs rewrite ---------------------------
// one block per row; 256 threads x 4 float4 = 4096 floats
__global__ __launch_bounds__(256)
void sc_probs_kernel(const float4*   __restrict__ probs4,
                     const float*    __restrict__ probs_s,   // scalar view for eos
                     const float*    __restrict__ rand_mask,
                     const unsigned* __restrict__ colhit_g,
                     float4*         __restrict__ out4)
{
    __shared__ unsigned colhit[V_DIM / 32];
    const int row = blockIdx.x;
    const int t   = threadIdx.x;

    if (t < V_DIM / 32) colhit[t] = colhit_g[t];
    __syncthreads();

    const bool m = rand_mask[row] < P_CONST;   // block-uniform
    const long rowbase4 = (long)row * (V_DIM / 4);

    if (m) {
        const float eos = probs_s[(long)row * V_DIM];
        const float om  = 1.0f - eos;
        #pragma unroll
        for (int k = 0; k < 4; ++k) {
            const int c4 = t + k * 256;            // float4 index in row
            const unsigned w = colhit[c4 >> 3];
            const int c0 = c4 * 4;
            float4 r;
            r.x = ((w >> ( c0      & 31)) & 1u) ? om : ((c0 == 0) ? eos : 0.0f);
            r.y = ((w >> ((c0 + 1) & 31)) & 1u) ? om : 0.0f;
            r.z = ((w >> ((c0 + 2) & 31)) & 1u) ? om : 0.0f;
            r.w = ((w >> ((c0 + 3) & 31)) & 1u) ? om : 0.0f;
            out4[rowbase4 + c4] = r;
        }
    } else {
        #pragma unroll
        for (int k = 0; k < 4; ++k) {
            const int c4 = t + k * 256;
            out4[rowbase4 + c4] = probs4[rowbase4 + c4];
        }
    }
}

extern "C" void kernel_launch(void* const* d_in, const int* in_sizes, int n_in,
                              void* d_out, int out_size, void* d_ws, size_t ws_size,
                              hipStream_t stream)
{
    const float* probs       = (const float*)d_in[0];
    const float* entropy     = (const float*)d_in[1];
    const float* rand_mask   = (const float*)d_in[2];
    const int*   repl        = (const int*)  d_in[3];

    float*    out        = (float*)d_out;
    float*    probs_out  = out;                       // B*L*V floats
    float*    entropy_out= out + (long)N_ROWS * V_DIM;
    unsigned* colhit_ws  = (unsigned*)d_ws;           // 128 words

    sc_colhit_kernel<<<1, 1024, 0, stream>>>(rand_mask, repl, entropy,
                                             colhit_ws, entropy_out);

    sc_probs_kernel<<<N_ROWS, 256, 0, stream>>>((const float4*)probs, probs,
                                                rand_mask, colhit_ws,
                                                (float4*)probs_out);
}